// Round 11
// baseline (398.934 us; speedup 1.0000x reference)
//
#include <hip/hip_runtime.h>

#define HH 128
#define WW 128
#define FEAT_OFF 2621440ull   // 16*10*128*128
#define ADJ_OFF  2623488ull   // FEAT_OFF + 16*128

typedef __bf16 bf16x8 __attribute__((ext_vector_type(8)));
typedef float  f32x4  __attribute__((ext_vector_type(4)));
typedef float  f32x16 __attribute__((ext_vector_type(16)));

__device__ __forceinline__ unsigned short f2bf(float f) {
  unsigned int u = __float_as_uint(f);
  unsigned int r = ((u >> 16) & 1u) + 0x7fffu;
  return (unsigned short)((u + r) >> 16);
}
__device__ __forceinline__ void gl_lds16(const void* g, void* l) {
  __builtin_amdgcn_global_load_lds((const __attribute__((address_space(1))) unsigned int*)g,
                                   (__attribute__((address_space(3))) unsigned int*)l, 16, 0, 0);
}
__device__ __forceinline__ int SW(int r) { return (r ^ (r >> 2)) & 3; }

#define FENCE() asm volatile("" ::: "memory")
#define BARRIER() do { FENCE(); __builtin_amdgcn_s_barrier(); FENCE(); } while (0)
#define LBAR() do { asm volatile("s_waitcnt lgkmcnt(0)" ::: "memory"); __builtin_amdgcn_s_barrier(); FENCE(); } while (0)

// ---------------- prep: weight repack (bf16) + zero page ----------------
__global__ void prep_kernel(const float* __restrict__ w1, const float* __restrict__ w2,
                            unsigned short* __restrict__ W1t, unsigned short* __restrict__ W2t,
                            unsigned short* __restrict__ zp) {
  int id = blockIdx.x * 256 + threadIdx.x;
  if (id < 2048) zp[id] = 0;
  if (id < 294912) {
    int ci = id & 255, co = (id >> 8) & 127, dxy = id >> 15;
    int dy = dxy / 3, dx = dxy - 3 * dy;
    W1t[id] = f2bf(w1[((co * 256 + ci) * 3 + dy) * 3 + dx]);
  }
  if (id < 18432) {
    int ci = id & 127, co = (id >> 7) & 15, dxy = id >> 11;
    int dy = dxy / 3, dx = dxy - 3 * dy;
    W2t[id] = (co < 10) ? f2bf(w2[((co * 128 + ci) * 3 + dy) * 3 + dx]) : (unsigned short)0;
  }
}

// ---------------- nhwc v4: full 256-ch blocks, perfect store coalescing + fused pool ----------------
// grid 2048 = (b 16) x (y 128), 512 threads. Dynamic LDS: tile 65536 B + pl 8192 B = 73728 B.
// part layout: [b][y][c*8+px] fp32 (2048 per (b,y))
__global__ void nhwc_kernel(const float* __restrict__ F, unsigned short* __restrict__ Xn,
                            float* __restrict__ part) {
  extern __shared__ __align__(16) unsigned short ntile[];  // [x 128][ch 256] ush, slot-swizzled
  float* pl = (float*)(ntile + 32768);                     // [c 256][px 8]
  int t = threadIdx.x;
  int y = blockIdx.x & 127, b = blockIdx.x >> 7;
  int cp = t >> 2, xq = t & 3;                             // ch-pair 0..127, x-quarter 0..3
  const float* rowA = F + (((size_t)(b * 256 + cp * 2)) * HH + y) * WW + xq * 32;
  const float* rowB = rowA + (size_t)HH * WW;
  unsigned int* tw = (unsigned int*)ntile;
  float s00 = 0.f, s01 = 0.f, s10 = 0.f, s11 = 0.f;
#pragma unroll
  for (int jj = 0; jj < 8; ++jj) {
    float4 va = *(const float4*)(rowA + jj * 4);
    float4 vb = *(const float4*)(rowB + jj * 4);
    float av[4] = {va.x, va.y, va.z, va.w};
    float bv[4] = {vb.x, vb.y, vb.z, vb.w};
#pragma unroll
    for (int e = 0; e < 4; ++e) {
      int xl = jj * 4 + e;
      int x = xq * 32 + xl;
      if (xl < 16) { s00 += av[e]; s10 += bv[e]; } else { s01 += av[e]; s11 += bv[e]; }
      unsigned int word = (unsigned int)f2bf(av[e]) | ((unsigned int)f2bf(bv[e]) << 16);
      tw[x * 128 + (((cp >> 2) ^ (x & 15)) << 2) + (cp & 3)] = word;
    }
  }
  pl[(cp * 2 + 0) * 8 + xq * 2 + 0] = s00;
  pl[(cp * 2 + 0) * 8 + xq * 2 + 1] = s01;
  pl[(cp * 2 + 1) * 8 + xq * 2 + 0] = s10;
  pl[(cp * 2 + 1) * 8 + xq * 2 + 1] = s11;
  __syncthreads();
  // phase B: thread (x = t>>2, sub = t&3) writes 128B contiguous; wave covers 8KB contiguous
  {
    int x = t >> 2, sub = t & 3;
    unsigned short* dst = Xn + ((((size_t)b * HH + y) * WW) + x) * 256 + sub * 64;
#pragma unroll
    for (int k = 0; k < 8; ++k) {
      int s = sub * 8 + k;                                 // 16B chunk 0..31
      *(uint4*)(dst + k * 8) = *(const uint4*)(ntile + x * 256 + ((s ^ (x & 15)) << 3));
    }
  }
  float* pd = part + ((size_t)b * 128 + y) * 2048;
  *(float4*)&pd[t * 4] = *(const float4*)&pl[t * 4];
}

// ---------------- pool3: reduce partials over y ----------------
// grid 128 = 16b x 8py, 256 threads
__global__ void pool3_kernel(const float* __restrict__ part, float* __restrict__ pooled) {
  int bi = blockIdx.x, t = threadIdx.x;
  int py = bi & 7, b = bi >> 3;
#pragma unroll
  for (int q = 0; q < 8; ++q) {
    int i = q * 256 + t;                                   // c*8+px
    float s = 0.f;
#pragma unroll
    for (int yy = 0; yy < 16; ++yy)
      s += part[((size_t)b * 128 + py * 16 + yy) * 2048 + i];
    int c = i >> 3, px = i & 7;
    pooled[(size_t)b * 16384 + c * 64 + py * 8 + px] = s * (1.f / 256.f);
  }
}

// ---------------- conv1: 32x32x16 MFMA, 3-slice interleave, 2 barriers/phase ----------------
// grid 512 (16 b x 32 yquads), 512 threads (8 waves: yloc=w>>1, xh=w&1), dbuf counted-vmcnt
__global__ __launch_bounds__(512) void conv1_kernel(const unsigned short* __restrict__ X,
                                                    const unsigned short* __restrict__ Wt,
                                                    const float* __restrict__ bias,
                                                    unsigned short* __restrict__ Hout,
                                                    const unsigned short* __restrict__ zp) {
  extern __shared__ __align__(16) unsigned short smem[];   // 2 * 30720 ush = 122880 B
  const int t = threadIdx.x, l = t & 63, w = t >> 6;
  int bid = (blockIdx.x & 7) * 64 + (blockIdx.x >> 3);     // XCD-bijective (512 = 8*64)
  const int b = bid >> 5, y0 = (bid & 31) * 4;
  const int lane31 = l & 31, lh = l >> 5;
  const int yloc = w >> 1, xh = w & 1, xoff = xh * 64;

  f32x16 acc[2][4];
#pragma unroll
  for (int i = 0; i < 2; ++i)
#pragma unroll
    for (int j = 0; j < 4; ++j)
#pragma unroll
      for (int e = 0; e < 16; ++e) acc[i][j][e] = 0.f;

  auto issue_group = [&](int p, int i0, int i1, int bufsel) {
    int dy = p >> 3, cb = p & 7;
    unsigned short* buf = smem + bufsel * 30720;
    for (int i = i0; i < i1; ++i) {
      int c = w + 8 * i;
      if (c >= 60) break;                                  // wave-uniform
      const unsigned short* g;
      if (c < 36) {                                        // A: air = c/9, jj = c%9
        int air = c / 9, jj = c - air * 9;
        int er = jj * 16 + (l >> 2);
        int xin = er - 1;
        int row = y0 - 1 + dy + air;
        if (row >= 0 && row < HH && xin >= 0 && xin < WW && er < 130) {
          int kq = (l & 3) ^ SW(er);
          g = X + (((size_t)b * HH + row) * WW + xin) * 256 + cb * 32 + kq * 8;
        } else g = zp + l * 8;
      } else {                                             // B: cc = c-36: dxi = cc>>3, jj = cc&7
        int cc = c - 36;
        int dxi = cc >> 3, jj = cc & 7;
        int co = jj * 16 + (l >> 2);
        int kq = (l & 3) ^ SW(co);
        g = Wt + (((size_t)(dy * 3 + dxi)) * 128 + co) * 256 + cb * 32 + kq * 8;
      }
      gl_lds16(g, buf + c * 512);
    }
  };

  issue_group(0, 0, 8, 0);                                 // full phase-0 stage

  for (int p = 0; p < 24; ++p) {
    const unsigned short* buf = smem + (p & 1) * 30720;
    const unsigned short* Ab = buf + yloc * 4608;          // own input row (air = yloc)
    const unsigned short* Bb = buf + 18432;
    const int nsel = (p + 1) & 1;

    // -- readiness: issue slice 0 of next phase, then counted wait + barrier --
    if (p < 23) issue_group(p + 1, 0, 3, nsel);
    FENCE();
    if (p < 23) asm volatile("s_waitcnt vmcnt(3)" ::: "memory");
    else        asm volatile("s_waitcnt vmcnt(0)" ::: "memory");
    BARRIER();

#pragma unroll
    for (int dx = 0; dx < 3; ++dx) {
      if (p < 23) {
        if (dx == 1)      issue_group(p + 1, 3, 6, nsel);
        else if (dx == 2) issue_group(p + 1, 6, 8, nsel);
      }
      bf16x8 a[2][2], bb[4][2];
#pragma unroll
      for (int tm = 0; tm < 2; ++tm)
#pragma unroll
        for (int ks = 0; ks < 2; ++ks) {
          int er = xoff + tm * 32 + lane31 + dx;
          int slot = (ks * 2 + lh) ^ SW(er);
          a[tm][ks] = *(const bf16x8*)(Ab + er * 32 + slot * 8);
        }
#pragma unroll
      for (int tn = 0; tn < 4; ++tn)
#pragma unroll
        for (int ks = 0; ks < 2; ++ks) {
          int co = tn * 32 + lane31;
          int slot = (ks * 2 + lh) ^ SW(co);
          bb[tn][ks] = *(const bf16x8*)(Bb + dx * 4096 + co * 32 + slot * 8);
        }
      __builtin_amdgcn_s_setprio(1);
#pragma unroll
      for (int ks = 0; ks < 2; ++ks)
#pragma unroll
        for (int tm = 0; tm < 2; ++tm)
#pragma unroll
          for (int tn = 0; tn < 4; ++tn)
            acc[tm][tn] = __builtin_amdgcn_mfma_f32_32x32x16_bf16(a[tm][ks], bb[tn][ks], acc[tm][tn], 0, 0, 0);
      __builtin_amdgcn_s_setprio(0);
    }
    BARRIER();                                             // end-of-phase WAR (buf p&1 reads done)
  }

  // epilogue: bias+relu -> bf16, E = [yloc 4][xl 64][co 128] pad-136; 2 rounds by xh
  // 32x32 C layout: col = lane31, row = (rr&3) + 8*(rr>>2) + 4*lh
  unsigned short* E = smem;
  for (int r = 0; r < 2; ++r) {
    if (xh == r) {
#pragma unroll
      for (int tn = 0; tn < 4; ++tn) {
        int co = tn * 32 + lane31;
        float bv = bias[co];
#pragma unroll
        for (int tm = 0; tm < 2; ++tm)
#pragma unroll
          for (int rr = 0; rr < 16; ++rr) {
            int row = (rr & 3) + 8 * (rr >> 2) + 4 * lh;
            int xl = tm * 32 + row;
            E[yloc * 8704 + xl * 136 + co] = f2bf(fmaxf(acc[tm][tn][rr] + bv, 0.f));
          }
      }
    }
    LBAR();
#pragma unroll
    for (int k = 0; k < 8; ++k) {
      int idx = k * 512 + t;                               // 0..4095
      int yl = idx >> 10, rem = idx & 1023;
      int xl = rem >> 4, oct = rem & 15;
      const uint4 v = *(const uint4*)(E + yl * 8704 + xl * 136 + oct * 8);
      size_t g = (((size_t)b * HH + y0 + yl) * WW + r * 64 + xl) * 128 + oct * 8;
      *(uint4*)(Hout + g) = v;
    }
    LBAR();
  }
}

// ---------------- conv2: dbuf, counted vmcnt, 4 rows x N=16 ----------------
__global__ __launch_bounds__(256) void conv2_kernel(const unsigned short* __restrict__ Hn,
                                                    const unsigned short* __restrict__ Wt,
                                                    const float* __restrict__ bias,
                                                    float* __restrict__ rmaps,
                                                    const unsigned short* __restrict__ zp) {
  extern __shared__ __align__(16) unsigned short smem[];   // 2 * 32256 ush = 129024 B
  const int t = threadIdx.x, l = t & 63, w = t >> 6;
  int bid = (blockIdx.x & 7) * 64 + (blockIdx.x >> 3);     // XCD-bijective (512 = 8*64)
  const int b = bid >> 5, y0 = (bid & 31) * 4;
  const int ko = l >> 4, r0 = l & 15;
  const int yloc = w;

  f32x4 acc[8];
#pragma unroll
  for (int i = 0; i < 8; ++i) acc[i] = {0.f, 0.f, 0.f, 0.f};

  auto stage = [&](int cb, int bufsel) {
    unsigned short* buf = smem + bufsel * 32256;
    for (int c = w; c < 63; c += 4) {
      const unsigned short* g;
      if (c < 54) {                                        // A: air = c/9 (rows y0-1..y0+4)
        int air = c / 9, jj = c - air * 9;
        int er = jj * 16 + (l >> 2);
        int xin = er - 1;
        int row = y0 - 1 + air;
        if (row >= 0 && row < HH && xin >= 0 && xin < WW && er < 130) {
          int kq = (l & 3) ^ SW(er);
          g = Hn + (((size_t)b * HH + row) * WW + xin) * 128 + cb * 32 + kq * 8;
        } else g = zp + l * 8;
      } else {                                             // W: tap = c-54
        int tap = c - 54;
        int co = l >> 2;
        int kq = (l & 3) ^ SW(co);
        g = Wt + ((size_t)tap * 16 + co) * 128 + cb * 32 + kq * 8;
      }
      gl_lds16(g, buf + c * 512);
    }
  };

  stage(0, 0);
  for (int p = 0; p < 4; ++p) {
    if (p < 3) {
      stage(p + 1, (p + 1) & 1);
      FENCE();
      asm volatile("s_waitcnt vmcnt(15)" ::: "memory");
    } else {
      FENCE();
      asm volatile("s_waitcnt vmcnt(0)" ::: "memory");
    }
    BARRIER();
    const unsigned short* buf = smem + (p & 1) * 32256;
#pragma unroll
    for (int dy = 0; dy < 3; ++dy) {
      const unsigned short* Ab = buf + (yloc + dy) * 4608;
#pragma unroll
      for (int dx = 0; dx < 3; ++dx) {
        int tap = dy * 3 + dx;
        bf16x8 bbf = *(const bf16x8*)(buf + (54 + tap) * 512 + r0 * 32 + ((ko ^ SW(r0)) << 3));
        __builtin_amdgcn_s_setprio(1);
#pragma unroll
        for (int mf = 0; mf < 8; ++mf) {
          int er = mf * 16 + r0 + dx;
          bf16x8 a = *(const bf16x8*)(Ab + er * 32 + ((ko ^ SW(er)) << 3));
          acc[mf] = __builtin_amdgcn_mfma_f32_16x16x32_bf16(a, bbf, acc[mf], 0, 0, 0);
        }
        __builtin_amdgcn_s_setprio(0);
      }
    }
    BARRIER();
  }

  int co = r0;
  if (co < 10) {
    float bv = bias[co];
    int y = y0 + yloc;
#pragma unroll
    for (int mf = 0; mf < 8; ++mf) {
      int x = mf * 16 + ko * 4;
      float4 o;
      o.x = 1.f / (1.f + __expf(-(acc[mf][0] + bv)));
      o.y = 1.f / (1.f + __expf(-(acc[mf][1] + bv)));
      o.z = 1.f / (1.f + __expf(-(acc[mf][2] + bv)));
      o.w = 1.f / (1.f + __expf(-(acc[mf][3] + bv)));
      *(float4*)&rmaps[(((size_t)b * 10 + co) * HH + y) * WW + x] = o;
    }
  }
}

// ---------------- lin1 ----------------
__global__ void lin1_kernel(const float* __restrict__ pooled, const float* __restrict__ w1,
                            const float* __restrict__ b1, float* __restrict__ hidden) {
  int o = blockIdx.x, t = threadIdx.x;
  float acc[16];
#pragma unroll
  for (int b = 0; b < 16; ++b) acc[b] = 0.f;
  const float* wr = w1 + (size_t)o * 16384;
  for (int i = t; i < 16384; i += 256) {
    float wv = wr[i];
#pragma unroll
    for (int b = 0; b < 16; ++b) acc[b] += wv * pooled[(size_t)b * 16384 + i];
  }
  __shared__ float red[16][4];
#pragma unroll
  for (int b = 0; b < 16; ++b) {
    float v = acc[b];
    for (int s = 32; s; s >>= 1) v += __shfl_down(v, s);
    if ((t & 63) == 0) red[b][t >> 6] = v;
  }
  __syncthreads();
  if (t < 16) {
    float v = red[t][0] + red[t][1] + red[t][2] + red[t][3] + b1[o];
    hidden[o * 16 + t] = fmaxf(v, 0.f);
  }
}

// ---------------- head ----------------
__global__ void head_kernel(const float* __restrict__ hidden,
                            const float* __restrict__ w2, const float* __restrict__ b2,
                            const float* __restrict__ a1w, const float* __restrict__ a1b,
                            const float* __restrict__ a2w, const float* __restrict__ a2b,
                            const float* __restrict__ a3w, const float* __restrict__ a3b,
                            float* __restrict__ out) {
  int b = blockIdx.x, t = threadIdx.x;
  __shared__ float hid[256], fs[128], a1[64], a2[32], pv;
  hid[t] = hidden[t * 16 + b];
  __syncthreads();
  if (t < 128) {
    float s = b2[t];
    for (int k = 0; k < 256; ++k) s += hid[k] * w2[t * 256 + k];
    fs[t] = s;
    out[FEAT_OFF + b * 128 + t] = s;
  }
  __syncthreads();
  if (t < 64) {
    float s = a1b[t];
    for (int k = 0; k < 128; ++k) s += fs[k] * (a1w[t * 256 + k] + a1w[t * 256 + 128 + k]);
    a1[t] = fmaxf(s, 0.f);
  }
  __syncthreads();
  if (t < 32) {
    float s = a2b[t];
    for (int k = 0; k < 64; ++k) s += a1[k] * a2w[t * 64 + k];
    a2[t] = fmaxf(s, 0.f);
  }
  __syncthreads();
  if (t == 0) {
    float s = a3b[0];
    for (int k = 0; k < 32; ++k) s += a2[k] * a3w[k];
    pv = 1.f / (1.f + __expf(-s));
  }
  __syncthreads();
  if (t < 100) out[ADJ_OFF + b * 100 + t] = ((t / 10) == (t % 10)) ? 0.f : pv;
}

extern "C" void kernel_launch(void* const* d_in, const int* in_sizes, int n_in,
                              void* d_out, int out_size, void* d_ws, size_t ws_size,
                              hipStream_t stream) {
  const float* F   = (const float*)d_in[0];
  const float* w1  = (const float*)d_in[1];
  const float* b1  = (const float*)d_in[2];
  const float* w2  = (const float*)d_in[3];
  const float* b2  = (const float*)d_in[4];
  const float* l1w = (const float*)d_in[5];
  const float* l1b = (const float*)d_in[6];
  const float* l2w = (const float*)d_in[7];
  const float* l2b = (const float*)d_in[8];
  const float* a1w = (const float*)d_in[9];
  const float* a1b = (const float*)d_in[10];
  const float* a2w = (const float*)d_in[11];
  const float* a2b = (const float*)d_in[12];
  const float* a3w = (const float*)d_in[13];
  const float* a3b = (const float*)d_in[14];
  float* out = (float*)d_out;
  char* ws = (char*)d_ws;

  const size_t zp_off   = 0;
  const size_t w1t_off  = 4096;
  const size_t w2t_off  = w1t_off + 589824;
  const size_t xn_off   = w2t_off + 36864;
  const size_t hn_off   = xn_off + 134217728ull;            // Hn (67 MB); aliased by part (16.8 MB, consumed pre-conv1)
  const size_t pool_off = hn_off + 67108864ull;
  const size_t hid_off  = pool_off + 1048576ull;
  const size_t need     = hid_off + 16384ull;
  if (ws_size < need) return;

  unsigned short* zp  = (unsigned short*)(ws + zp_off);
  unsigned short* W1t = (unsigned short*)(ws + w1t_off);
  unsigned short* W2t = (unsigned short*)(ws + w2t_off);
  unsigned short* Xn  = (unsigned short*)(ws + xn_off);
  unsigned short* Hn  = (unsigned short*)(ws + hn_off);
  float* part   = (float*)(ws + hn_off);                    // alias: dead once pool3 ran
  float* pooled = (float*)(ws + pool_off);
  float* hidden = (float*)(ws + hid_off);

  hipFuncSetAttribute((const void*)nhwc_kernel,  hipFuncAttributeMaxDynamicSharedMemorySize, 73728);
  hipFuncSetAttribute((const void*)conv1_kernel, hipFuncAttributeMaxDynamicSharedMemorySize, 122880);
  hipFuncSetAttribute((const void*)conv2_kernel, hipFuncAttributeMaxDynamicSharedMemorySize, 129024);

  prep_kernel<<<1152, 256, 0, stream>>>(w1, w2, W1t, W2t, zp);
  nhwc_kernel<<<2048, 512, 73728, stream>>>(F, Xn, part);
  pool3_kernel<<<128, 256, 0, stream>>>(part, pooled);
  conv1_kernel<<<512, 512, 122880, stream>>>(Xn, W1t, b1, Hn, zp);
  conv2_kernel<<<512, 256, 129024, stream>>>(Hn, W2t, b2, out, zp);
  lin1_kernel<<<256, 256, 0, stream>>>(pooled, l1w, l1b, hidden);
  head_kernel<<<16, 256, 0, stream>>>(hidden, l2w, l2b, a1w, a1b, a2w, a2b, a3w, a3b, out);
}

// Round 12
// 367.094 us; speedup vs baseline: 1.0867x; 1.0867x over previous
//
#include <hip/hip_runtime.h>

#define HH 128
#define WW 128
#define FEAT_OFF 2621440ull   // 16*10*128*128
#define ADJ_OFF  2623488ull   // FEAT_OFF + 16*128

typedef __bf16 bf16x8 __attribute__((ext_vector_type(8)));
typedef float  f32x4  __attribute__((ext_vector_type(4)));
typedef float  f32x16 __attribute__((ext_vector_type(16)));

__device__ __forceinline__ unsigned short f2bf(float f) {
  unsigned int u = __float_as_uint(f);
  unsigned int r = ((u >> 16) & 1u) + 0x7fffu;
  return (unsigned short)((u + r) >> 16);
}
__device__ __forceinline__ void gl_lds16(const void* g, void* l) {
  __builtin_amdgcn_global_load_lds((const __attribute__((address_space(1))) unsigned int*)g,
                                   (__attribute__((address_space(3))) unsigned int*)l, 16, 0, 0);
}
__device__ __forceinline__ int SW(int r) { return (r ^ (r >> 2)) & 3; }

#define FENCE() asm volatile("" ::: "memory")
#define BARRIER() do { FENCE(); __builtin_amdgcn_s_barrier(); FENCE(); } while (0)
#define LBAR() do { asm volatile("s_waitcnt lgkmcnt(0)" ::: "memory"); __builtin_amdgcn_s_barrier(); FENCE(); } while (0)

// ---------------- prep: weight repack (bf16) + zero page ----------------
__global__ void prep_kernel(const float* __restrict__ w1, const float* __restrict__ w2,
                            unsigned short* __restrict__ W1t, unsigned short* __restrict__ W2t,
                            unsigned short* __restrict__ zp) {
  int id = blockIdx.x * 256 + threadIdx.x;
  if (id < 2048) zp[id] = 0;
  if (id < 294912) {
    int ci = id & 255, co = (id >> 8) & 127, dxy = id >> 15;
    int dy = dxy / 3, dx = dxy - 3 * dy;
    W1t[id] = f2bf(w1[((co * 256 + ci) * 3 + dy) * 3 + dx]);
  }
  if (id < 18432) {
    int ci = id & 127, co = (id >> 7) & 15, dxy = id >> 11;
    int dy = dxy / 3, dx = dxy - 3 * dy;
    W2t[id] = (co < 10) ? f2bf(w2[((co * 128 + ci) * 3 + dy) * 3 + dx]) : (unsigned short)0;
  }
}

// ---------------- NCHW fp32 -> NHWC bf16 via LDS transpose + fused pool (r10 proven) ----------------
// grid: 16b x 128y x 2 chalf = 4096 blocks, 256 threads
__global__ void nhwc_kernel(const float* __restrict__ F, unsigned short* __restrict__ Xn,
                            float* __restrict__ part) {
  __shared__ __align__(16) unsigned short tile[16384];   // [x 128][ch 128] ush, slot-swizzled
  __shared__ float pl[1024];                             // [ch 128][px 8]
  int t = threadIdx.x, bi = blockIdx.x;
  int chalf = bi & 1, y = (bi >> 1) & 127, b = bi >> 8;
  int c0 = chalf * 128;
  int cp = t >> 2, xq = t & 3;
  const float* rowA = F + (((size_t)(b * 256 + c0 + cp * 2)) * HH + y) * WW + xq * 32;
  const float* rowB = rowA + (size_t)HH * WW;
  unsigned int* tw = (unsigned int*)tile;
  float s00 = 0.f, s01 = 0.f, s10 = 0.f, s11 = 0.f;
#pragma unroll
  for (int jj = 0; jj < 8; ++jj) {
    float4 va = *(const float4*)(rowA + jj * 4);
    float4 vb = *(const float4*)(rowB + jj * 4);
    float av[4] = {va.x, va.y, va.z, va.w};
    float bv[4] = {vb.x, vb.y, vb.z, vb.w};
#pragma unroll
    for (int e = 0; e < 4; ++e) {
      int xl = jj * 4 + e;
      int x = xq * 32 + xl;
      if (xl < 16) { s00 += av[e]; s10 += bv[e]; } else { s01 += av[e]; s11 += bv[e]; }
      unsigned int word = (unsigned int)f2bf(av[e]) | ((unsigned int)f2bf(bv[e]) << 16);
      tw[x * 64 + (((cp >> 2) ^ (x & 15)) << 2) + (cp & 3)] = word;
    }
  }
  pl[(cp * 2 + 0) * 8 + xq * 2 + 0] = s00;
  pl[(cp * 2 + 0) * 8 + xq * 2 + 1] = s01;
  pl[(cp * 2 + 1) * 8 + xq * 2 + 0] = s10;
  pl[(cp * 2 + 1) * 8 + xq * 2 + 1] = s11;
  __syncthreads();
  int x = t >> 1, h = t & 1;
  unsigned short* dst = Xn + ((((size_t)b * HH + y) * WW) + x) * 256 + c0;
#pragma unroll
  for (int k = 0; k < 8; ++k) {
    int s = h * 8 + k;
    *(uint4*)(dst + s * 8) = *(const uint4*)(tile + x * 128 + ((s ^ (x & 15)) << 3));
  }
  *(float4*)&part[((((size_t)b * 128 + y) * 2) + chalf) * 1024 + t * 4] = *(const float4*)&pl[t * 4];
}

// ---------------- pool3: reduce partials over y (r10 proven) ----------------
// grid 256 = 16b x 2 chalf x 8 py, 256 threads
__global__ void pool3_kernel(const float* __restrict__ part, float* __restrict__ pooled) {
  int bi = blockIdx.x, t = threadIdx.x;
  int py = bi & 7, chalf = (bi >> 3) & 1, b = bi >> 4;
#pragma unroll
  for (int q = 0; q < 4; ++q) {
    int i = q * 256 + t;
    float s = 0.f;
#pragma unroll
    for (int yy = 0; yy < 16; ++yy)
      s += part[((((size_t)b * 128 + py * 16 + yy) * 2) + chalf) * 1024 + i];
    int ch = i >> 3, px = i & 7;
    pooled[(size_t)b * 16384 + (chalf * 128 + ch) * 64 + py * 8 + px] = s * (1.f / 256.f);
  }
}

// ---------------- conv1: 32x32x16 MFMA, 3-slice interleave, 2 barriers/phase (r11 proven) ----------------
// grid 512 (16 b x 32 yquads), 512 threads (8 waves: yloc=w>>1, xh=w&1), dbuf counted-vmcnt
__global__ __launch_bounds__(512) void conv1_kernel(const unsigned short* __restrict__ X,
                                                    const unsigned short* __restrict__ Wt,
                                                    const float* __restrict__ bias,
                                                    unsigned short* __restrict__ Hout,
                                                    const unsigned short* __restrict__ zp) {
  extern __shared__ __align__(16) unsigned short smem[];   // 2 * 30720 ush = 122880 B
  const int t = threadIdx.x, l = t & 63, w = t >> 6;
  int bid = (blockIdx.x & 7) * 64 + (blockIdx.x >> 3);     // XCD-bijective (512 = 8*64)
  const int b = bid >> 5, y0 = (bid & 31) * 4;
  const int lane31 = l & 31, lh = l >> 5;
  const int yloc = w >> 1, xh = w & 1, xoff = xh * 64;

  f32x16 acc[2][4];
#pragma unroll
  for (int i = 0; i < 2; ++i)
#pragma unroll
    for (int j = 0; j < 4; ++j)
#pragma unroll
      for (int e = 0; e < 16; ++e) acc[i][j][e] = 0.f;

  auto issue_group = [&](int p, int i0, int i1, int bufsel) {
    int dy = p >> 3, cb = p & 7;
    unsigned short* buf = smem + bufsel * 30720;
    for (int i = i0; i < i1; ++i) {
      int c = w + 8 * i;
      if (c >= 60) break;                                  // wave-uniform
      const unsigned short* g;
      if (c < 36) {                                        // A: air = c/9, jj = c%9
        int air = c / 9, jj = c - air * 9;
        int er = jj * 16 + (l >> 2);
        int xin = er - 1;
        int row = y0 - 1 + dy + air;
        if (row >= 0 && row < HH && xin >= 0 && xin < WW && er < 130) {
          int kq = (l & 3) ^ SW(er);
          g = X + (((size_t)b * HH + row) * WW + xin) * 256 + cb * 32 + kq * 8;
        } else g = zp + l * 8;
      } else {                                             // B: cc = c-36: dxi = cc>>3, jj = cc&7
        int cc = c - 36;
        int dxi = cc >> 3, jj = cc & 7;
        int co = jj * 16 + (l >> 2);
        int kq = (l & 3) ^ SW(co);
        g = Wt + (((size_t)(dy * 3 + dxi)) * 128 + co) * 256 + cb * 32 + kq * 8;
      }
      gl_lds16(g, buf + c * 512);
    }
  };

  issue_group(0, 0, 8, 0);                                 // full phase-0 stage

  for (int p = 0; p < 24; ++p) {
    const unsigned short* buf = smem + (p & 1) * 30720;
    const unsigned short* Ab = buf + yloc * 4608;          // own input row (air = yloc)
    const unsigned short* Bb = buf + 18432;
    const int nsel = (p + 1) & 1;

    // -- readiness: issue slice 0 of next phase, then counted wait + barrier --
    if (p < 23) issue_group(p + 1, 0, 3, nsel);
    FENCE();
    if (p < 23) asm volatile("s_waitcnt vmcnt(3)" ::: "memory");
    else        asm volatile("s_waitcnt vmcnt(0)" ::: "memory");
    BARRIER();

#pragma unroll
    for (int dx = 0; dx < 3; ++dx) {
      if (p < 23) {
        if (dx == 1)      issue_group(p + 1, 3, 6, nsel);
        else if (dx == 2) issue_group(p + 1, 6, 8, nsel);
      }
      bf16x8 a[2][2], bb[4][2];
#pragma unroll
      for (int tm = 0; tm < 2; ++tm)
#pragma unroll
        for (int ks = 0; ks < 2; ++ks) {
          int er = xoff + tm * 32 + lane31 + dx;
          int slot = (ks * 2 + lh) ^ SW(er);
          a[tm][ks] = *(const bf16x8*)(Ab + er * 32 + slot * 8);
        }
#pragma unroll
      for (int tn = 0; tn < 4; ++tn)
#pragma unroll
        for (int ks = 0; ks < 2; ++ks) {
          int co = tn * 32 + lane31;
          int slot = (ks * 2 + lh) ^ SW(co);
          bb[tn][ks] = *(const bf16x8*)(Bb + dx * 4096 + co * 32 + slot * 8);
        }
      __builtin_amdgcn_s_setprio(1);
#pragma unroll
      for (int ks = 0; ks < 2; ++ks)
#pragma unroll
        for (int tm = 0; tm < 2; ++tm)
#pragma unroll
          for (int tn = 0; tn < 4; ++tn)
            acc[tm][tn] = __builtin_amdgcn_mfma_f32_32x32x16_bf16(a[tm][ks], bb[tn][ks], acc[tm][tn], 0, 0, 0);
      __builtin_amdgcn_s_setprio(0);
    }
    BARRIER();                                             // end-of-phase WAR (buf p&1 reads done)
  }

  // epilogue: bias+relu -> bf16, E = [yloc 4][xl 64][co 128] pad-136; 2 rounds by xh
  // 32x32 C layout: col = lane31, row = (rr&3) + 8*(rr>>2) + 4*lh
  unsigned short* E = smem;
  for (int r = 0; r < 2; ++r) {
    if (xh == r) {
#pragma unroll
      for (int tn = 0; tn < 4; ++tn) {
        int co = tn * 32 + lane31;
        float bv = bias[co];
#pragma unroll
        for (int tm = 0; tm < 2; ++tm)
#pragma unroll
          for (int rr = 0; rr < 16; ++rr) {
            int row = (rr & 3) + 8 * (rr >> 2) + 4 * lh;
            int xl = tm * 32 + row;
            E[yloc * 8704 + xl * 136 + co] = f2bf(fmaxf(acc[tm][tn][rr] + bv, 0.f));
          }
      }
    }
    LBAR();
#pragma unroll
    for (int k = 0; k < 8; ++k) {
      int idx = k * 512 + t;                               // 0..4095
      int yl = idx >> 10, rem = idx & 1023;
      int xl = rem >> 4, oct = rem & 15;
      const uint4 v = *(const uint4*)(E + yl * 8704 + xl * 136 + oct * 8);
      size_t g = (((size_t)b * HH + y0 + yl) * WW + r * 64 + xl) * 128 + oct * 8;
      *(uint4*)(Hout + g) = v;
    }
    LBAR();
  }
}

// ---------------- conv2: dbuf, counted vmcnt, 4 rows x N=16 ----------------
__global__ __launch_bounds__(256) void conv2_kernel(const unsigned short* __restrict__ Hn,
                                                    const unsigned short* __restrict__ Wt,
                                                    const float* __restrict__ bias,
                                                    float* __restrict__ rmaps,
                                                    const unsigned short* __restrict__ zp) {
  extern __shared__ __align__(16) unsigned short smem[];   // 2 * 32256 ush = 129024 B
  const int t = threadIdx.x, l = t & 63, w = t >> 6;
  int bid = (blockIdx.x & 7) * 64 + (blockIdx.x >> 3);     // XCD-bijective (512 = 8*64)
  const int b = bid >> 5, y0 = (bid & 31) * 4;
  const int ko = l >> 4, r0 = l & 15;
  const int yloc = w;

  f32x4 acc[8];
#pragma unroll
  for (int i = 0; i < 8; ++i) acc[i] = {0.f, 0.f, 0.f, 0.f};

  auto stage = [&](int cb, int bufsel) {
    unsigned short* buf = smem + bufsel * 32256;
    for (int c = w; c < 63; c += 4) {
      const unsigned short* g;
      if (c < 54) {                                        // A: air = c/9 (rows y0-1..y0+4)
        int air = c / 9, jj = c - air * 9;
        int er = jj * 16 + (l >> 2);
        int xin = er - 1;
        int row = y0 - 1 + air;
        if (row >= 0 && row < HH && xin >= 0 && xin < WW && er < 130) {
          int kq = (l & 3) ^ SW(er);
          g = Hn + (((size_t)b * HH + row) * WW + xin) * 128 + cb * 32 + kq * 8;
        } else g = zp + l * 8;
      } else {                                             // W: tap = c-54
        int tap = c - 54;
        int co = l >> 2;
        int kq = (l & 3) ^ SW(co);
        g = Wt + ((size_t)tap * 16 + co) * 128 + cb * 32 + kq * 8;
      }
      gl_lds16(g, buf + c * 512);
    }
  };

  stage(0, 0);
  for (int p = 0; p < 4; ++p) {
    if (p < 3) {
      stage(p + 1, (p + 1) & 1);
      FENCE();
      asm volatile("s_waitcnt vmcnt(15)" ::: "memory");
    } else {
      FENCE();
      asm volatile("s_waitcnt vmcnt(0)" ::: "memory");
    }
    BARRIER();
    const unsigned short* buf = smem + (p & 1) * 32256;
#pragma unroll
    for (int dy = 0; dy < 3; ++dy) {
      const unsigned short* Ab = buf + (yloc + dy) * 4608;
#pragma unroll
      for (int dx = 0; dx < 3; ++dx) {
        int tap = dy * 3 + dx;
        bf16x8 bbf = *(const bf16x8*)(buf + (54 + tap) * 512 + r0 * 32 + ((ko ^ SW(r0)) << 3));
        __builtin_amdgcn_s_setprio(1);
#pragma unroll
        for (int mf = 0; mf < 8; ++mf) {
          int er = mf * 16 + r0 + dx;
          bf16x8 a = *(const bf16x8*)(Ab + er * 32 + ((ko ^ SW(er)) << 3));
          acc[mf] = __builtin_amdgcn_mfma_f32_16x16x32_bf16(a, bbf, acc[mf], 0, 0, 0);
        }
        __builtin_amdgcn_s_setprio(0);
      }
    }
    BARRIER();
  }

  int co = r0;
  if (co < 10) {
    float bv = bias[co];
    int y = y0 + yloc;
#pragma unroll
    for (int mf = 0; mf < 8; ++mf) {
      int x = mf * 16 + ko * 4;
      float4 o;
      o.x = 1.f / (1.f + __expf(-(acc[mf][0] + bv)));
      o.y = 1.f / (1.f + __expf(-(acc[mf][1] + bv)));
      o.z = 1.f / (1.f + __expf(-(acc[mf][2] + bv)));
      o.w = 1.f / (1.f + __expf(-(acc[mf][3] + bv)));
      *(float4*)&rmaps[(((size_t)b * 10 + co) * HH + y) * WW + x] = o;
    }
  }
}

// ---------------- lin1 ----------------
__global__ void lin1_kernel(const float* __restrict__ pooled, const float* __restrict__ w1,
                            const float* __restrict__ b1, float* __restrict__ hidden) {
  int o = blockIdx.x, t = threadIdx.x;
  float acc[16];
#pragma unroll
  for (int b = 0; b < 16; ++b) acc[b] = 0.f;
  const float* wr = w1 + (size_t)o * 16384;
  for (int i = t; i < 16384; i += 256) {
    float wv = wr[i];
#pragma unroll
    for (int b = 0; b < 16; ++b) acc[b] += wv * pooled[(size_t)b * 16384 + i];
  }
  __shared__ float red[16][4];
#pragma unroll
  for (int b = 0; b < 16; ++b) {
    float v = acc[b];
    for (int s = 32; s; s >>= 1) v += __shfl_down(v, s);
    if ((t & 63) == 0) red[b][t >> 6] = v;
  }
  __syncthreads();
  if (t < 16) {
    float v = red[t][0] + red[t][1] + red[t][2] + red[t][3] + b1[o];
    hidden[o * 16 + t] = fmaxf(v, 0.f);
  }
}

// ---------------- head ----------------
__global__ void head_kernel(const float* __restrict__ hidden,
                            const float* __restrict__ w2, const float* __restrict__ b2,
                            const float* __restrict__ a1w, const float* __restrict__ a1b,
                            const float* __restrict__ a2w, const float* __restrict__ a2b,
                            const float* __restrict__ a3w, const float* __restrict__ a3b,
                            float* __restrict__ out) {
  int b = blockIdx.x, t = threadIdx.x;
  __shared__ float hid[256], fs[128], a1[64], a2[32], pv;
  hid[t] = hidden[t * 16 + b];
  __syncthreads();
  if (t < 128) {
    float s = b2[t];
    for (int k = 0; k < 256; ++k) s += hid[k] * w2[t * 256 + k];
    fs[t] = s;
    out[FEAT_OFF + b * 128 + t] = s;
  }
  __syncthreads();
  if (t < 64) {
    float s = a1b[t];
    for (int k = 0; k < 128; ++k) s += fs[k] * (a1w[t * 256 + k] + a1w[t * 256 + 128 + k]);
    a1[t] = fmaxf(s, 0.f);
  }
  __syncthreads();
  if (t < 32) {
    float s = a2b[t];
    for (int k = 0; k < 64; ++k) s += a1[k] * a2w[t * 64 + k];
    a2[t] = fmaxf(s, 0.f);
  }
  __syncthreads();
  if (t == 0) {
    float s = a3b[0];
    for (int k = 0; k < 32; ++k) s += a2[k] * a3w[k];
    pv = 1.f / (1.f + __expf(-s));
  }
  __syncthreads();
  if (t < 100) out[ADJ_OFF + b * 100 + t] = ((t / 10) == (t % 10)) ? 0.f : pv;
}

extern "C" void kernel_launch(void* const* d_in, const int* in_sizes, int n_in,
                              void* d_out, int out_size, void* d_ws, size_t ws_size,
                              hipStream_t stream) {
  const float* F   = (const float*)d_in[0];
  const float* w1  = (const float*)d_in[1];
  const float* b1  = (const float*)d_in[2];
  const float* w2  = (const float*)d_in[3];
  const float* b2  = (const float*)d_in[4];
  const float* l1w = (const float*)d_in[5];
  const float* l1b = (const float*)d_in[6];
  const float* l2w = (const float*)d_in[7];
  const float* l2b = (const float*)d_in[8];
  const float* a1w = (const float*)d_in[9];
  const float* a1b = (const float*)d_in[10];
  const float* a2w = (const float*)d_in[11];
  const float* a2b = (const float*)d_in[12];
  const float* a3w = (const float*)d_in[13];
  const float* a3b = (const float*)d_in[14];
  float* out = (float*)d_out;
  char* ws = (char*)d_ws;

  const size_t zp_off   = 0;
  const size_t w1t_off  = 4096;
  const size_t w2t_off  = w1t_off + 589824;
  const size_t xn_off   = w2t_off + 36864;
  const size_t hn_off   = xn_off + 134217728ull;            // Hn (67 MB); aliased by part (16.8 MB, consumed pre-conv1)
  const size_t pool_off = hn_off + 67108864ull;
  const size_t hid_off  = pool_off + 1048576ull;
  const size_t need     = hid_off + 16384ull;
  if (ws_size < need) return;

  unsigned short* zp  = (unsigned short*)(ws + zp_off);
  unsigned short* W1t = (unsigned short*)(ws + w1t_off);
  unsigned short* W2t = (unsigned short*)(ws + w2t_off);
  unsigned short* Xn  = (unsigned short*)(ws + xn_off);
  unsigned short* Hn  = (unsigned short*)(ws + hn_off);
  float* part   = (float*)(ws + hn_off);                    // alias: dead once pool3 ran
  float* pooled = (float*)(ws + pool_off);
  float* hidden = (float*)(ws + hid_off);

  hipFuncSetAttribute((const void*)conv1_kernel, hipFuncAttributeMaxDynamicSharedMemorySize, 122880);
  hipFuncSetAttribute((const void*)conv2_kernel, hipFuncAttributeMaxDynamicSharedMemorySize, 129024);

  prep_kernel<<<1152, 256, 0, stream>>>(w1, w2, W1t, W2t, zp);
  nhwc_kernel<<<4096, 256, 0, stream>>>(F, Xn, part);
  pool3_kernel<<<256, 256, 0, stream>>>(part, pooled);
  conv1_kernel<<<512, 512, 122880, stream>>>(Xn, W1t, b1, Hn, zp);
  conv2_kernel<<<512, 256, 129024, stream>>>(Hn, W2t, b2, out, zp);
  lin1_kernel<<<256, 256, 0, stream>>>(pooled, l1w, l1b, hidden);
  head_kernel<<<16, 256, 0, stream>>>(hidden, l2w, l2b, a1w, a1b, a2w, a2b, a3w, a3b, out);
}

// Round 13
// 340.236 us; speedup vs baseline: 1.1725x; 1.0789x over previous
//
#include <hip/hip_runtime.h>

#define HH 128
#define WW 128
#define FEAT_OFF 2621440ull   // 16*10*128*128
#define ADJ_OFF  2623488ull   // FEAT_OFF + 16*128

typedef __bf16 bf16x8 __attribute__((ext_vector_type(8)));
typedef float  f32x4  __attribute__((ext_vector_type(4)));
typedef float  f32x16 __attribute__((ext_vector_type(16)));

__device__ __forceinline__ unsigned short f2bf(float f) {
  unsigned int u = __float_as_uint(f);
  unsigned int r = ((u >> 16) & 1u) + 0x7fffu;
  return (unsigned short)((u + r) >> 16);
}
__device__ __forceinline__ void gl_lds16(const void* g, void* l) {
  __builtin_amdgcn_global_load_lds((const __attribute__((address_space(1))) unsigned int*)g,
                                   (__attribute__((address_space(3))) unsigned int*)l, 16, 0, 0);
}
__device__ __forceinline__ int SW(int r) { return (r ^ (r >> 2)) & 3; }

#define FENCE() asm volatile("" ::: "memory")
#define BARRIER() do { FENCE(); __builtin_amdgcn_s_barrier(); FENCE(); } while (0)
#define LBAR() do { asm volatile("s_waitcnt lgkmcnt(0)" ::: "memory"); __builtin_amdgcn_s_barrier(); FENCE(); } while (0)

// ---------------- NCHW fp32 -> NHWC bf16 via LDS transpose + fused pool + fused prep ----------------
// grid: 16b x 128y x 2 chalf = 4096 blocks, 256 threads
__global__ void nhwc_kernel(const float* __restrict__ F, unsigned short* __restrict__ Xn,
                            float* __restrict__ part,
                            const float* __restrict__ w1, const float* __restrict__ w2,
                            unsigned short* __restrict__ W1t, unsigned short* __restrict__ W2t,
                            unsigned short* __restrict__ zp) {
  __shared__ __align__(16) unsigned short tile[16384];   // [x 128][ch 128] ush, slot-swizzled
  __shared__ float pl[1024];                             // [ch 128][px 8]
  int t = threadIdx.x, bi = blockIdx.x;
  // fused prep (independent of transform work; blocks 0..1151)
  if (bi < 1152) {
    int id = bi * 256 + t;
    if (id < 2048) zp[id] = 0;
    if (id < 294912) {
      int ci = id & 255, co = (id >> 8) & 127, dxy = id >> 15;
      int dy = dxy / 3, dx = dxy - 3 * dy;
      W1t[id] = f2bf(w1[((co * 256 + ci) * 3 + dy) * 3 + dx]);
    }
    if (id < 18432) {
      int ci = id & 127, co = (id >> 7) & 15, dxy = id >> 11;
      int dy = dxy / 3, dx = dxy - 3 * dy;
      W2t[id] = (co < 10) ? f2bf(w2[((co * 128 + ci) * 3 + dy) * 3 + dx]) : (unsigned short)0;
    }
  }
  int chalf = bi & 1, y = (bi >> 1) & 127, b = bi >> 8;
  int c0 = chalf * 128;
  int cp = t >> 2, xq = t & 3;
  const float* rowA = F + (((size_t)(b * 256 + c0 + cp * 2)) * HH + y) * WW + xq * 32;
  const float* rowB = rowA + (size_t)HH * WW;
  unsigned int* tw = (unsigned int*)tile;
  float s00 = 0.f, s01 = 0.f, s10 = 0.f, s11 = 0.f;
#pragma unroll
  for (int jj = 0; jj < 8; ++jj) {
    float4 va = *(const float4*)(rowA + jj * 4);
    float4 vb = *(const float4*)(rowB + jj * 4);
    float av[4] = {va.x, va.y, va.z, va.w};
    float bv[4] = {vb.x, vb.y, vb.z, vb.w};
#pragma unroll
    for (int e = 0; e < 4; ++e) {
      int xl = jj * 4 + e;
      int x = xq * 32 + xl;
      if (xl < 16) { s00 += av[e]; s10 += bv[e]; } else { s01 += av[e]; s11 += bv[e]; }
      unsigned int word = (unsigned int)f2bf(av[e]) | ((unsigned int)f2bf(bv[e]) << 16);
      tw[x * 64 + (((cp >> 2) ^ (x & 15)) << 2) + (cp & 3)] = word;
    }
  }
  pl[(cp * 2 + 0) * 8 + xq * 2 + 0] = s00;
  pl[(cp * 2 + 0) * 8 + xq * 2 + 1] = s01;
  pl[(cp * 2 + 1) * 8 + xq * 2 + 0] = s10;
  pl[(cp * 2 + 1) * 8 + xq * 2 + 1] = s11;
  __syncthreads();
  int x = t >> 1, h = t & 1;
  unsigned short* dst = Xn + ((((size_t)b * HH + y) * WW) + x) * 256 + c0;
#pragma unroll
  for (int k = 0; k < 8; ++k) {
    int s = h * 8 + k;
    *(uint4*)(dst + s * 8) = *(const uint4*)(tile + x * 128 + ((s ^ (x & 15)) << 3));
  }
  *(float4*)&part[((((size_t)b * 128 + y) * 2) + chalf) * 1024 + t * 4] = *(const float4*)&pl[t * 4];
}

// ---------------- pool3: reduce partials over y; writes pooled AND pooledT[i][b] ----------------
// grid 256 = 16b x 2 chalf x 8 py, 256 threads
__global__ void pool3_kernel(const float* __restrict__ part, float* __restrict__ pooled,
                             float* __restrict__ pooledT) {
  int bi = blockIdx.x, t = threadIdx.x;
  int py = bi & 7, chalf = (bi >> 3) & 1, b = bi >> 4;
#pragma unroll
  for (int q = 0; q < 4; ++q) {
    int i = q * 256 + t;
    float s = 0.f;
#pragma unroll
    for (int yy = 0; yy < 16; ++yy)
      s += part[((((size_t)b * 128 + py * 16 + yy) * 2) + chalf) * 1024 + i];
    int ch = i >> 3, px = i & 7;
    float v = s * (1.f / 256.f);
    int flat = (chalf * 128 + ch) * 64 + py * 8 + px;
    pooled[(size_t)b * 16384 + flat] = v;
    pooledT[(size_t)flat * 16 + b] = v;
  }
}

// ---------------- conv1: 32x32x16 MFMA, 3-slice interleave, 2 barriers/phase (r11/r12 proven) ----------------
// grid 512 (16 b x 32 yquads), 512 threads (8 waves: yloc=w>>1, xh=w&1), dbuf counted-vmcnt
__global__ __launch_bounds__(512) void conv1_kernel(const unsigned short* __restrict__ X,
                                                    const unsigned short* __restrict__ Wt,
                                                    const float* __restrict__ bias,
                                                    unsigned short* __restrict__ Hout,
                                                    const unsigned short* __restrict__ zp) {
  extern __shared__ __align__(16) unsigned short smem[];   // 2 * 30720 ush = 122880 B
  const int t = threadIdx.x, l = t & 63, w = t >> 6;
  int bid = (blockIdx.x & 7) * 64 + (blockIdx.x >> 3);     // XCD-bijective (512 = 8*64)
  const int b = bid >> 5, y0 = (bid & 31) * 4;
  const int lane31 = l & 31, lh = l >> 5;
  const int yloc = w >> 1, xh = w & 1, xoff = xh * 64;

  f32x16 acc[2][4];
#pragma unroll
  for (int i = 0; i < 2; ++i)
#pragma unroll
    for (int j = 0; j < 4; ++j)
#pragma unroll
      for (int e = 0; e < 16; ++e) acc[i][j][e] = 0.f;

  auto issue_group = [&](int p, int i0, int i1, int bufsel) {
    int dy = p >> 3, cb = p & 7;
    unsigned short* buf = smem + bufsel * 30720;
    for (int i = i0; i < i1; ++i) {
      int c = w + 8 * i;
      if (c >= 60) break;                                  // wave-uniform
      const unsigned short* g;
      if (c < 36) {                                        // A: air = c/9, jj = c%9
        int air = c / 9, jj = c - air * 9;
        int er = jj * 16 + (l >> 2);
        int xin = er - 1;
        int row = y0 - 1 + dy + air;
        if (row >= 0 && row < HH && xin >= 0 && xin < WW && er < 130) {
          int kq = (l & 3) ^ SW(er);
          g = X + (((size_t)b * HH + row) * WW + xin) * 256 + cb * 32 + kq * 8;
        } else g = zp + l * 8;
      } else {                                             // B: cc = c-36: dxi = cc>>3, jj = cc&7
        int cc = c - 36;
        int dxi = cc >> 3, jj = cc & 7;
        int co = jj * 16 + (l >> 2);
        int kq = (l & 3) ^ SW(co);
        g = Wt + (((size_t)(dy * 3 + dxi)) * 128 + co) * 256 + cb * 32 + kq * 8;
      }
      gl_lds16(g, buf + c * 512);
    }
  };

  issue_group(0, 0, 8, 0);                                 // full phase-0 stage

  for (int p = 0; p < 24; ++p) {
    const unsigned short* buf = smem + (p & 1) * 30720;
    const unsigned short* Ab = buf + yloc * 4608;          // own input row (air = yloc)
    const unsigned short* Bb = buf + 18432;
    const int nsel = (p + 1) & 1;

    // -- readiness: issue slice 0 of next phase, then counted wait + barrier --
    if (p < 23) issue_group(p + 1, 0, 3, nsel);
    FENCE();
    if (p < 23) asm volatile("s_waitcnt vmcnt(3)" ::: "memory");
    else        asm volatile("s_waitcnt vmcnt(0)" ::: "memory");
    BARRIER();

#pragma unroll
    for (int dx = 0; dx < 3; ++dx) {
      if (p < 23) {
        if (dx == 1)      issue_group(p + 1, 3, 6, nsel);
        else if (dx == 2) issue_group(p + 1, 6, 8, nsel);
      }
      bf16x8 a[2][2], bb[4][2];
#pragma unroll
      for (int tm = 0; tm < 2; ++tm)
#pragma unroll
        for (int ks = 0; ks < 2; ++ks) {
          int er = xoff + tm * 32 + lane31 + dx;
          int slot = (ks * 2 + lh) ^ SW(er);
          a[tm][ks] = *(const bf16x8*)(Ab + er * 32 + slot * 8);
        }
#pragma unroll
      for (int tn = 0; tn < 4; ++tn)
#pragma unroll
        for (int ks = 0; ks < 2; ++ks) {
          int co = tn * 32 + lane31;
          int slot = (ks * 2 + lh) ^ SW(co);
          bb[tn][ks] = *(const bf16x8*)(Bb + dx * 4096 + co * 32 + slot * 8);
        }
      __builtin_amdgcn_s_setprio(1);
#pragma unroll
      for (int ks = 0; ks < 2; ++ks)
#pragma unroll
        for (int tm = 0; tm < 2; ++tm)
#pragma unroll
          for (int tn = 0; tn < 4; ++tn)
            acc[tm][tn] = __builtin_amdgcn_mfma_f32_32x32x16_bf16(a[tm][ks], bb[tn][ks], acc[tm][tn], 0, 0, 0);
      __builtin_amdgcn_s_setprio(0);
    }
    BARRIER();                                             // end-of-phase WAR (buf p&1 reads done)
  }

  // epilogue: bias+relu -> bf16, E = [yloc 4][xl 64][co 128] pad-136; 2 rounds by xh
  // 32x32 C layout: col = lane31, row = (rr&3) + 8*(rr>>2) + 4*lh
  unsigned short* E = smem;
  for (int r = 0; r < 2; ++r) {
    if (xh == r) {
#pragma unroll
      for (int tn = 0; tn < 4; ++tn) {
        int co = tn * 32 + lane31;
        float bv = bias[co];
#pragma unroll
        for (int tm = 0; tm < 2; ++tm)
#pragma unroll
          for (int rr = 0; rr < 16; ++rr) {
            int row = (rr & 3) + 8 * (rr >> 2) + 4 * lh;
            int xl = tm * 32 + row;
            E[yloc * 8704 + xl * 136 + co] = f2bf(fmaxf(acc[tm][tn][rr] + bv, 0.f));
          }
      }
    }
    LBAR();
#pragma unroll
    for (int k = 0; k < 8; ++k) {
      int idx = k * 512 + t;                               // 0..4095
      int yl = idx >> 10, rem = idx & 1023;
      int xl = rem >> 4, oct = rem & 15;
      const uint4 v = *(const uint4*)(E + yl * 8704 + xl * 136 + oct * 8);
      size_t g = (((size_t)b * HH + y0 + yl) * WW + r * 64 + xl) * 128 + oct * 8;
      *(uint4*)(Hout + g) = v;
    }
    LBAR();
  }
}

// ---------------- conv2: dbuf, exact counted vmcnt, no setprio, 4 rows x N=16 ----------------
__global__ __launch_bounds__(256) void conv2_kernel(const unsigned short* __restrict__ Hn,
                                                    const unsigned short* __restrict__ Wt,
                                                    const float* __restrict__ bias,
                                                    float* __restrict__ rmaps,
                                                    const unsigned short* __restrict__ zp) {
  extern __shared__ __align__(16) unsigned short smem[];   // 2 * 32256 ush = 129024 B
  const int t = threadIdx.x, l = t & 63, w = t >> 6;
  int bid = (blockIdx.x & 7) * 64 + (blockIdx.x >> 3);     // XCD-bijective (512 = 8*64)
  const int b = bid >> 5, y0 = (bid & 31) * 4;
  const int ko = l >> 4, r0 = l & 15;
  const int yloc = w;

  f32x4 acc[8];
#pragma unroll
  for (int i = 0; i < 8; ++i) acc[i] = {0.f, 0.f, 0.f, 0.f};

  auto stage = [&](int cb, int bufsel) {
    unsigned short* buf = smem + bufsel * 32256;
    for (int c = w; c < 63; c += 4) {
      const unsigned short* g;
      if (c < 54) {                                        // A: air = c/9 (rows y0-1..y0+4)
        int air = c / 9, jj = c - air * 9;
        int er = jj * 16 + (l >> 2);
        int xin = er - 1;
        int row = y0 - 1 + air;
        if (row >= 0 && row < HH && xin >= 0 && xin < WW && er < 130) {
          int kq = (l & 3) ^ SW(er);
          g = Hn + (((size_t)b * HH + row) * WW + xin) * 128 + cb * 32 + kq * 8;
        } else g = zp + l * 8;
      } else {                                             // W: tap = c-54
        int tap = c - 54;
        int co = l >> 2;
        int kq = (l & 3) ^ SW(co);
        g = Wt + ((size_t)tap * 16 + co) * 128 + cb * 32 + kq * 8;
      }
      gl_lds16(g, buf + c * 512);
    }
  };

  stage(0, 0);
  for (int p = 0; p < 4; ++p) {
    if (p < 3) {
      stage(p + 1, (p + 1) & 1);
      FENCE();
      if (w < 3) asm volatile("s_waitcnt vmcnt(16)" ::: "memory");  // own 16 new loads in flight
      else       asm volatile("s_waitcnt vmcnt(15)" ::: "memory");  // wave 3 has 15
    } else {
      FENCE();
      asm volatile("s_waitcnt vmcnt(0)" ::: "memory");
    }
    BARRIER();
    const unsigned short* buf = smem + (p & 1) * 32256;
#pragma unroll
    for (int dy = 0; dy < 3; ++dy) {
      const unsigned short* Ab = buf + (yloc + dy) * 4608;
#pragma unroll
      for (int dx = 0; dx < 3; ++dx) {
        int tap = dy * 3 + dx;
        bf16x8 bbf = *(const bf16x8*)(buf + (54 + tap) * 512 + r0 * 32 + ((ko ^ SW(r0)) << 3));
#pragma unroll
        for (int mf = 0; mf < 8; ++mf) {
          int er = mf * 16 + r0 + dx;
          bf16x8 a = *(const bf16x8*)(Ab + er * 32 + ((ko ^ SW(er)) << 3));
          acc[mf] = __builtin_amdgcn_mfma_f32_16x16x32_bf16(a, bbf, acc[mf], 0, 0, 0);
        }
      }
    }
    BARRIER();
  }

  int co = r0;
  if (co < 10) {
    float bv = bias[co];
    int y = y0 + yloc;
#pragma unroll
    for (int mf = 0; mf < 8; ++mf) {
      int x = mf * 16 + ko * 4;
      float4 o;
      o.x = 1.f / (1.f + __expf(-(acc[mf][0] + bv)));
      o.y = 1.f / (1.f + __expf(-(acc[mf][1] + bv)));
      o.z = 1.f / (1.f + __expf(-(acc[mf][2] + bv)));
      o.w = 1.f / (1.f + __expf(-(acc[mf][3] + bv)));
      *(float4*)&rmaps[(((size_t)b * 10 + co) * HH + y) * WW + x] = o;
    }
  }
}

// ---------------- lin1: vectorized via pooledT[i][b16] ----------------
__global__ void lin1_kernel(const float* __restrict__ pooledT, const float* __restrict__ w1,
                            const float* __restrict__ b1, float* __restrict__ hidden) {
  int o = blockIdx.x, t = threadIdx.x;
  f32x4 acc[4];
#pragma unroll
  for (int q = 0; q < 4; ++q) acc[q] = {0.f, 0.f, 0.f, 0.f};
  const float* wr = w1 + (size_t)o * 16384;
  for (int i0 = t * 4; i0 < 16384; i0 += 1024) {
    float4 wv = *(const float4*)&wr[i0];
    float wa[4] = {wv.x, wv.y, wv.z, wv.w};
#pragma unroll
    for (int j = 0; j < 4; ++j) {
      const float* pt = pooledT + (size_t)(i0 + j) * 16;
#pragma unroll
      for (int q = 0; q < 4; ++q) {
        f32x4 pv = *(const f32x4*)(pt + q * 4);
#pragma unroll
        for (int e = 0; e < 4; ++e) acc[q][e] += wa[j] * pv[e];
      }
    }
  }
  __shared__ float red[16][4];
#pragma unroll
  for (int q = 0; q < 4; ++q)
#pragma unroll
    for (int e = 0; e < 4; ++e) {
      float v = acc[q][e];
      for (int s = 32; s; s >>= 1) v += __shfl_down(v, s);
      if ((t & 63) == 0) red[q * 4 + e][t >> 6] = v;
    }
  __syncthreads();
  if (t < 16) {
    float v = red[t][0] + red[t][1] + red[t][2] + red[t][3] + b1[o];
    hidden[o * 16 + t] = fmaxf(v, 0.f);
  }
}

// ---------------- head ----------------
__global__ void head_kernel(const float* __restrict__ hidden,
                            const float* __restrict__ w2, const float* __restrict__ b2,
                            const float* __restrict__ a1w, const float* __restrict__ a1b,
                            const float* __restrict__ a2w, const float* __restrict__ a2b,
                            const float* __restrict__ a3w, const float* __restrict__ a3b,
                            float* __restrict__ out) {
  int b = blockIdx.x, t = threadIdx.x;
  __shared__ float hid[256], fs[128], a1[64], a2[32], pv;
  hid[t] = hidden[t * 16 + b];
  __syncthreads();
  if (t < 128) {
    float s = b2[t];
    for (int k = 0; k < 256; ++k) s += hid[k] * w2[t * 256 + k];
    fs[t] = s;
    out[FEAT_OFF + b * 128 + t] = s;
  }
  __syncthreads();
  if (t < 64) {
    float s = a1b[t];
    for (int k = 0; k < 128; ++k) s += fs[k] * (a1w[t * 256 + k] + a1w[t * 256 + 128 + k]);
    a1[t] = fmaxf(s, 0.f);
  }
  __syncthreads();
  if (t < 32) {
    float s = a2b[t];
    for (int k = 0; k < 64; ++k) s += a1[k] * a2w[t * 64 + k];
    a2[t] = fmaxf(s, 0.f);
  }
  __syncthreads();
  if (t == 0) {
    float s = a3b[0];
    for (int k = 0; k < 32; ++k) s += a2[k] * a3w[k];
    pv = 1.f / (1.f + __expf(-s));
  }
  __syncthreads();
  if (t < 100) out[ADJ_OFF + b * 100 + t] = ((t / 10) == (t % 10)) ? 0.f : pv;
}

extern "C" void kernel_launch(void* const* d_in, const int* in_sizes, int n_in,
                              void* d_out, int out_size, void* d_ws, size_t ws_size,
                              hipStream_t stream) {
  const float* F   = (const float*)d_in[0];
  const float* w1  = (const float*)d_in[1];
  const float* b1  = (const float*)d_in[2];
  const float* w2  = (const float*)d_in[3];
  const float* b2  = (const float*)d_in[4];
  const float* l1w = (const float*)d_in[5];
  const float* l1b = (const float*)d_in[6];
  const float* l2w = (const float*)d_in[7];
  const float* l2b = (const float*)d_in[8];
  const float* a1w = (const float*)d_in[9];
  const float* a1b = (const float*)d_in[10];
  const float* a2w = (const float*)d_in[11];
  const float* a2b = (const float*)d_in[12];
  const float* a3w = (const float*)d_in[13];
  const float* a3b = (const float*)d_in[14];
  float* out = (float*)d_out;
  char* ws = (char*)d_ws;

  const size_t zp_off   = 0;
  const size_t w1t_off  = 4096;
  const size_t w2t_off  = w1t_off + 589824;
  const size_t xn_off   = w2t_off + 36864;
  const size_t hn_off   = xn_off + 134217728ull;            // Hn (67 MB); aliased by part (16.8 MB, consumed pre-conv1)
  const size_t pool_off = hn_off + 67108864ull;
  const size_t poolT_off= pool_off + 1048576ull;
  const size_t hid_off  = poolT_off + 1048576ull;
  const size_t need     = hid_off + 16384ull;
  if (ws_size < need) return;

  unsigned short* zp  = (unsigned short*)(ws + zp_off);
  unsigned short* W1t = (unsigned short*)(ws + w1t_off);
  unsigned short* W2t = (unsigned short*)(ws + w2t_off);
  unsigned short* Xn  = (unsigned short*)(ws + xn_off);
  unsigned short* Hn  = (unsigned short*)(ws + hn_off);
  float* part    = (float*)(ws + hn_off);                   // alias: dead once pool3 ran
  float* pooled  = (float*)(ws + pool_off);
  float* pooledT = (float*)(ws + poolT_off);
  float* hidden  = (float*)(ws + hid_off);
  (void)pooled;

  hipFuncSetAttribute((const void*)conv1_kernel, hipFuncAttributeMaxDynamicSharedMemorySize, 122880);
  hipFuncSetAttribute((const void*)conv2_kernel, hipFuncAttributeMaxDynamicSharedMemorySize, 129024);

  nhwc_kernel<<<4096, 256, 0, stream>>>(F, Xn, part, w1, w2, W1t, W2t, zp);
  pool3_kernel<<<256, 256, 0, stream>>>(part, pooled, pooledT);
  conv1_kernel<<<512, 512, 122880, stream>>>(Xn, W1t, b1, Hn, zp);
  conv2_kernel<<<512, 256, 129024, stream>>>(Hn, W2t, b2, out, zp);
  lin1_kernel<<<256, 256, 0, stream>>>(pooledT, l1w, l1b, hidden);
  head_kernel<<<16, 256, 0, stream>>>(hidden, l2w, l2b, a1w, a1b, a2w, a2b, a3w, a3b, out);
}